// Round 7
// baseline (723.978 us; speedup 1.0000x reference)
//
#include <hip/hip_runtime.h>
#include <stdint.h>

// Problem constants (QSGDLinear): out = x @ W^T
//   x: (2,1024,4096) fp32 -> M=2048, K=4096
//   ternary: (16384,4096) int32 in {-1,0,1} -> N=16384
//   scales: (16384*4096/128,) fp32, group = contiguous 128 along K of one row
#define M_ROWS 2048
#define IN_F   4096
#define OUT_F  16384

#define BM 128
#define BN 128
#define BK 64

typedef __attribute__((ext_vector_type(8))) short short8;     // 8 bf16 = 4 VGPRs
typedef __attribute__((ext_vector_type(4))) short short4v;    // 4 bf16 = 8 B
typedef __attribute__((ext_vector_type(16))) float floatx16;  // 32x32 MFMA acc

__device__ __forceinline__ unsigned short f32_to_bf16_rne(float f) {
    union { float f; uint32_t u; } v; v.f = f;
    uint32_t u = v.u;
    return (unsigned short)((u + 0x7FFFu + ((u >> 16) & 1u)) >> 16);
}

// ---- fused prepass: x fp32->bf16, W = ternary*scale -> bf16 ----
// (unchanged from R6: 16 B read / 8 B write per lane per iteration, coalesced)
__global__ __launch_bounds__(256) void prep_kernel(
        const float* __restrict__ x, const int* __restrict__ tern,
        const float* __restrict__ scales,
        unsigned short* __restrict__ xb, unsigned short* __restrict__ wb) {
    const int NX4 = M_ROWS * IN_F / 4;             // 2,097,152 float4 chunks
    const int NW4 = OUT_F * (IN_F / 4);            // 16,777,216 int4 chunks
    const int t   = blockIdx.x * 256 + threadIdx.x;

    for (int i = t; i < NX4; i += 524288) {
        float4 a = ((const float4*)x)[i];
        short4v o;
        o[0] = (short)f32_to_bf16_rne(a.x);
        o[1] = (short)f32_to_bf16_rne(a.y);
        o[2] = (short)f32_to_bf16_rne(a.z);
        o[3] = (short)f32_to_bf16_rne(a.w);
        ((short4v*)xb)[i] = o;
    }

    for (int i = t; i < NW4; i += 524288) {
        float s = scales[i >> 5];                  // 32 chunks (128 elems)/group
        int4 v = ((const int4*)tern)[i];
        short4v o;
        o[0] = (short)f32_to_bf16_rne((float)v.x * s);
        o[1] = (short)f32_to_bf16_rne((float)v.y * s);
        o[2] = (short)f32_to_bf16_rne((float)v.z * s);
        o[3] = (short)f32_to_bf16_rne((float)v.w * s);
        ((short4v*)wb)[i] = o;
    }
}

// ---- GEMM: C[M,N] = A[M,K] * B[N,K]^T, bf16 in / fp32 out ----
// R0/R6 m97 structure (278 us, MfmaUtil 44%, 0 bank conflicts) with ONE
// change: 16x16x32 MFMA -> 32x32x16 MFMA. Same wave tile (64x64 = 2x2 frags
// of 32x32), same LDS layout/traffic, same 64 acc regs, but half the MFMA
// instructions at 25% higher FLOP/cyc (m119: 2495 vs 2176 TF) -> ~20% less
// MFMA-pipe time for identical math.
// Fragment layouts:
//   A in:  lane l holds row l&31, k = (l>>5)*8 + e  (analog of verified
//          16x16x32 mapping row=l&15, k=(l>>4)*8+e)
//   B in:  col l&31, k = (l>>5)*8 + e
//   C/D:   col = lane&31, row = (reg&3) + 8*(reg>>2) + 4*(lane>>5)  [m74/m101]
// LDS XOR swizzle unchanged: slot (row, j) holds global k-chunk j ^ (row&7).
// Per 16-lane phase the bank pattern equals the verified conflict-free one.
__global__ __launch_bounds__(256, 4) void gemm_bt_kernel(
        const unsigned short* __restrict__ A,   // [M_ROWS][IN_F] bf16 bits
        const unsigned short* __restrict__ B,   // [OUT_F][IN_F] bf16 bits
        float* __restrict__ C) {                // [M_ROWS][OUT_F] fp32
    __shared__ unsigned short As[BM * BK];      // 16 KB
    __shared__ unsigned short Bs[BN * BK];      // 16 KB

    const int tid   = threadIdx.x;
    const int lane  = tid & 63;
    const int half  = lane >> 5;       // k-chunk selector within 16-k step
    const int row32 = lane & 31;       // fragment row/col
    const int w     = tid >> 6;        // wave 0..3
    const int wm    = (w & 1) * 64;
    const int wn    = (w >> 1) * 64;

    const int bm = blockIdx.x * BM;    // m fastest -> 16 consecutive blocks share a B tile
    const int bn = blockIdx.y * BN;

    floatx16 acc[2][2] = {};

    // Precompute LDS fragment element-offsets (constant over kt).
    // k-step ks in 0..3 (K=16 each); global k-chunk j = ks*2 + half.
    int a_off[4][2], b_off[4][2];
#pragma unroll
    for (int ks = 0; ks < 4; ++ks) {
        const int j = ks * 2 + half;
#pragma unroll
        for (int fb = 0; fb < 2; ++fb) {
            const int ra = wm + fb * 32 + row32;
            const int rb = wn + fb * 32 + row32;
            a_off[ks][fb] = ra * BK + ((j ^ (ra & 7)) << 3);
            b_off[ks][fb] = rb * BK + ((j ^ (rb & 7)) << 3);
        }
    }

    for (int kt = 0; kt < IN_F; kt += BK) {
        __syncthreads();
        // stage 32 KB: 2048 chunks of 16 B; 8 global_load_lds per thread
#pragma unroll
        for (int i = 0; i < 4; ++i) {
            const int c    = 256 * i + tid;       // chunk id (per lane)
            const int crow = c >> 3;              // tile row 0..127
            const int jg   = (c & 7) ^ (crow & 7);// swizzled global k-chunk
            const int ub   = (256 * i + (tid & 192)) * 8; // wave-uniform LDS base (elems)
            const unsigned short* ga =
                A + (size_t)(bm + crow) * IN_F + kt + jg * 8;
            const unsigned short* gb =
                B + (size_t)(bn + crow) * IN_F + kt + jg * 8;
            __builtin_amdgcn_global_load_lds(
                (const __attribute__((address_space(1))) void*)ga,
                (__attribute__((address_space(3))) void*)(As + ub), 16, 0, 0);
            __builtin_amdgcn_global_load_lds(
                (const __attribute__((address_space(1))) void*)gb,
                (__attribute__((address_space(3))) void*)(Bs + ub), 16, 0, 0);
        }
        __syncthreads();
        // compute: 4 k-steps (K=16) of 4 MFMAs
#pragma unroll
        for (int ks = 0; ks < 4; ++ks) {
            short8 af[2], bf[2];
#pragma unroll
            for (int fb = 0; fb < 2; ++fb) {
                af[fb] = *(const short8*)(As + a_off[ks][fb]);
                bf[fb] = *(const short8*)(Bs + b_off[ks][fb]);
            }
#pragma unroll
            for (int mb = 0; mb < 2; ++mb)
#pragma unroll
                for (int nb = 0; nb < 2; ++nb)
                    acc[mb][nb] = __builtin_amdgcn_mfma_f32_32x32x16_bf16(
                        af[mb], bf[nb], acc[mb][nb], 0, 0, 0);
        }
    }

    // epilogue: C/D col = lane&31, row = (reg&3) + 8*(reg>>2) + 4*(lane>>5)
    const int col0 = bn + wn + row32;
    const int rbase = bm + wm + 4 * half;
#pragma unroll
    for (int mb = 0; mb < 2; ++mb) {
#pragma unroll
        for (int nb = 0; nb < 2; ++nb) {
            float* cp = C + (size_t)(rbase + mb * 32) * OUT_F + (col0 + nb * 32);
#pragma unroll
            for (int r = 0; r < 16; ++r) {
                const int rr = (r & 3) + 8 * (r >> 2);
                cp[(size_t)rr * OUT_F] = acc[mb][nb][r];
            }
        }
    }
}

extern "C" void kernel_launch(void* const* d_in, const int* in_sizes, int n_in,
                              void* d_out, int out_size, void* d_ws, size_t ws_size,
                              hipStream_t stream) {
    const float* x     = (const float*)d_in[0];
    const int*   tern  = (const int*)d_in[1];
    const float* scal  = (const float*)d_in[2];
    float*       out   = (float*)d_out;

    // workspace: x_bf16 (16 MB) then w_bf16 (128 MB)
    unsigned short* xb = (unsigned short*)d_ws;
    unsigned short* wb = xb + (size_t)M_ROWS * IN_F;

    prep_kernel<<<2048, 256, 0, stream>>>(x, tern, scal, xb, wb);
    gemm_bt_kernel<<<dim3(M_ROWS / BM, OUT_F / BN), 256, 0, stream>>>(xb, wb, out);
}

// Round 8
// 699.646 us; speedup vs baseline: 1.0348x; 1.0348x over previous
//
#include <hip/hip_runtime.h>
#include <stdint.h>

// Problem constants (QSGDLinear): out = x @ W^T
//   x: (2,1024,4096) fp32 -> M=2048, K=4096
//   ternary: (16384,4096) int32 in {-1,0,1} -> N=16384
//   scales: (16384*4096/128,) fp32, group = contiguous 128 along K of one row
#define M_ROWS 2048
#define IN_F   4096
#define OUT_F  16384

#define BM 128
#define BN 128
#define BK 64

typedef __attribute__((ext_vector_type(8))) short short8;     // 8 bf16 = 4 VGPRs
typedef __attribute__((ext_vector_type(4))) short short4v;    // 4 bf16 = 8 B
typedef __attribute__((ext_vector_type(16))) float floatx16;  // 32x32 MFMA acc

__device__ __forceinline__ unsigned short f32_to_bf16_rne(float f) {
    union { float f; uint32_t u; } v; v.f = f;
    uint32_t u = v.u;
    return (unsigned short)((u + 0x7FFFu + ((u >> 16) & 1u)) >> 16);
}

// ---- fused prepass: x fp32->bf16, W = ternary*scale -> bf16 ----
// (unchanged: 16 B read / 8 B write per lane per iteration, coalesced)
__global__ __launch_bounds__(256) void prep_kernel(
        const float* __restrict__ x, const int* __restrict__ tern,
        const float* __restrict__ scales,
        unsigned short* __restrict__ xb, unsigned short* __restrict__ wb) {
    const int NX4 = M_ROWS * IN_F / 4;             // 2,097,152 float4 chunks
    const int NW4 = OUT_F * (IN_F / 4);            // 16,777,216 int4 chunks
    const int t   = blockIdx.x * 256 + threadIdx.x;

    for (int i = t; i < NX4; i += 524288) {
        float4 a = ((const float4*)x)[i];
        short4v o;
        o[0] = (short)f32_to_bf16_rne(a.x);
        o[1] = (short)f32_to_bf16_rne(a.y);
        o[2] = (short)f32_to_bf16_rne(a.z);
        o[3] = (short)f32_to_bf16_rne(a.w);
        ((short4v*)xb)[i] = o;
    }

    for (int i = t; i < NW4; i += 524288) {
        float s = scales[i >> 5];                  // 32 chunks (128 elems)/group
        int4 v = ((const int4*)tern)[i];
        short4v o;
        o[0] = (short)f32_to_bf16_rne((float)v.x * s);
        o[1] = (short)f32_to_bf16_rne((float)v.y * s);
        o[2] = (short)f32_to_bf16_rne((float)v.z * s);
        o[3] = (short)f32_to_bf16_rne((float)v.w * s);
        ((short4v*)wb)[i] = o;
    }
}

// ---- GEMM: C[M,N] = A[M,K] * B[N,K]^T, bf16 in / fp32 out ----
// R7 (32x32x16 MFMA) with ONE change: LDS swizzle f(row) = (row^(row>>3))&7
// instead of row&7. R7's 3.35e7 bank conflicts came from all 32 lanes of a
// fragment sharing j: lanes {l,l+8,l+16,l+24} (rows = mod 8) hit the SAME
// 16B slot -> 4-way conflict. New f differs across rows 8 apart (via
// (row>>3)&3) while 8 consecutive rows still cover all 8 slots; worst-case
// 2-way for any plausible 16-lane phase grouping (free, m136).
// R7 PMC showed MFMA busy ~= R6 (127 vs 124 us) -> 32x32 ran at throughput;
// conflict stall was the entire regression. Expect its removal + fewer
// MFMA-pipe cycles (16x8.07 vs 32x4.85 cyc/tile/wave) to land ~255-265 us.
// Fragment layouts (verified in R7, absmax 0.0625):
//   A in:  lane l holds row l&31, k = (l>>5)*8 + e
//   B in:  col l&31, k = (l>>5)*8 + e
//   C/D:   col = lane&31, row = (reg&3) + 8*(reg>>2) + 4*(lane>>5)  [m74/m101]
__global__ __launch_bounds__(256, 4) void gemm_bt_kernel(
        const unsigned short* __restrict__ A,   // [M_ROWS][IN_F] bf16 bits
        const unsigned short* __restrict__ B,   // [OUT_F][IN_F] bf16 bits
        float* __restrict__ C) {                // [M_ROWS][OUT_F] fp32
    __shared__ unsigned short As[BM * BK];      // 16 KB
    __shared__ unsigned short Bs[BN * BK];      // 16 KB

    const int tid   = threadIdx.x;
    const int lane  = tid & 63;
    const int half  = lane >> 5;       // k-chunk selector within 16-k step
    const int row32 = lane & 31;       // fragment row/col
    const int w     = tid >> 6;        // wave 0..3
    const int wm    = (w & 1) * 64;
    const int wn    = (w >> 1) * 64;

    const int bm = blockIdx.x * BM;    // m fastest -> 16 consecutive blocks share a B tile
    const int bn = blockIdx.y * BN;

    floatx16 acc[2][2] = {};

    // Precompute LDS fragment element-offsets (constant over kt).
    // k-step ks in 0..3 (K=16 each); global k-chunk j = ks*2 + half.
    // LDS slot of global chunk j in row r: j ^ f(r), f(r) = (r^(r>>3))&7.
    int a_off[4][2], b_off[4][2];
#pragma unroll
    for (int ks = 0; ks < 4; ++ks) {
        const int j = ks * 2 + half;
#pragma unroll
        for (int fb = 0; fb < 2; ++fb) {
            const int ra = wm + fb * 32 + row32;
            const int rb = wn + fb * 32 + row32;
            a_off[ks][fb] = ra * BK + ((j ^ ((ra ^ (ra >> 3)) & 7)) << 3);
            b_off[ks][fb] = rb * BK + ((j ^ ((rb ^ (rb >> 3)) & 7)) << 3);
        }
    }

    for (int kt = 0; kt < IN_F; kt += BK) {
        __syncthreads();
        // stage 32 KB: 2048 chunks of 16 B; 8 global_load_lds per thread
#pragma unroll
        for (int i = 0; i < 4; ++i) {
            const int c    = 256 * i + tid;       // chunk id (per lane)
            const int crow = c >> 3;              // tile row 0..127
            const int jg   = (c & 7) ^ ((crow ^ (crow >> 3)) & 7); // swizzled chunk
            const int ub   = (256 * i + (tid & 192)) * 8; // wave-uniform LDS base (elems)
            const unsigned short* ga =
                A + (size_t)(bm + crow) * IN_F + kt + jg * 8;
            const unsigned short* gb =
                B + (size_t)(bn + crow) * IN_F + kt + jg * 8;
            __builtin_amdgcn_global_load_lds(
                (const __attribute__((address_space(1))) void*)ga,
                (__attribute__((address_space(3))) void*)(As + ub), 16, 0, 0);
            __builtin_amdgcn_global_load_lds(
                (const __attribute__((address_space(1))) void*)gb,
                (__attribute__((address_space(3))) void*)(Bs + ub), 16, 0, 0);
        }
        __syncthreads();
        // compute: 4 k-steps (K=16) of 4 MFMAs
#pragma unroll
        for (int ks = 0; ks < 4; ++ks) {
            short8 af[2], bf[2];
#pragma unroll
            for (int fb = 0; fb < 2; ++fb) {
                af[fb] = *(const short8*)(As + a_off[ks][fb]);
                bf[fb] = *(const short8*)(Bs + b_off[ks][fb]);
            }
#pragma unroll
            for (int mb = 0; mb < 2; ++mb)
#pragma unroll
                for (int nb = 0; nb < 2; ++nb)
                    acc[mb][nb] = __builtin_amdgcn_mfma_f32_32x32x16_bf16(
                        af[mb], bf[nb], acc[mb][nb], 0, 0, 0);
        }
    }

    // epilogue: C/D col = lane&31, row = (reg&3) + 8*(reg>>2) + 4*(lane>>5)
    const int col0 = bn + wn + row32;
    const int rbase = bm + wm + 4 * half;
#pragma unroll
    for (int mb = 0; mb < 2; ++mb) {
#pragma unroll
        for (int nb = 0; nb < 2; ++nb) {
            float* cp = C + (size_t)(rbase + mb * 32) * OUT_F + (col0 + nb * 32);
#pragma unroll
            for (int r = 0; r < 16; ++r) {
                const int rr = (r & 3) + 8 * (r >> 2);
                cp[(size_t)rr * OUT_F] = acc[mb][nb][r];
            }
        }
    }
}

extern "C" void kernel_launch(void* const* d_in, const int* in_sizes, int n_in,
                              void* d_out, int out_size, void* d_ws, size_t ws_size,
                              hipStream_t stream) {
    const float* x     = (const float*)d_in[0];
    const int*   tern  = (const int*)d_in[1];
    const float* scal  = (const float*)d_in[2];
    float*       out   = (float*)d_out;

    // workspace: x_bf16 (16 MB) then w_bf16 (128 MB)
    unsigned short* xb = (unsigned short*)d_ws;
    unsigned short* wb = xb + (size_t)M_ROWS * IN_F;

    prep_kernel<<<2048, 256, 0, stream>>>(x, tern, scal, xb, wb);
    gemm_bt_kernel<<<dim3(M_ROWS / BM, OUT_F / BN), 256, 0, stream>>>(xb, wb, out);
}